// Round 1
// baseline (1318.965 us; speedup 1.0000x reference)
//
#include <hip/hip_runtime.h>
#include <hip/hip_bf16.h>

// Problem constants (from reference)
#define GN 20000          // nodes
#define GE 320000         // edges (without self loops)
#define GETOT (GE + GN)   // edges + self loops
#define GH 4              // heads

// ---------------------------------------------------------------------------
// edge_index dtype detection: JAX may deliver int64 or (x64-disabled) int32.
// If data is int32, interpreting pairs as int64 gives lo + hi*2^32 with hi a
// random src index in [0,20000) -> value out of [0,N) with overwhelming prob.
// ---------------------------------------------------------------------------
__global__ void detect_dtype_kernel(const void* __restrict__ ei, int* __restrict__ flag) {
    if (threadIdx.x == 0 && blockIdx.x == 0) {
        const long long* p = (const long long*)ei;
        int ok = 1;
        for (int i = 0; i < 16; ++i) {
            long long v = p[i];
            if (v < 0 || v >= GN) ok = 0;
        }
        *flag = ok;  // 1 => int64 layout, 0 => int32 layout
    }
}

__device__ __forceinline__ int load_idx(const void* ei, int is64, long long pos) {
    if (is64) return (int)((const long long*)ei)[pos];
    return ((const int*)ei)[pos];
}

// ---------------------------------------------------------------------------
// CSR build: histogram by dst, exclusive scan, scatter src ids
// ---------------------------------------------------------------------------
__global__ void hist_kernel(const void* __restrict__ ei, const int* __restrict__ flagp,
                            int* __restrict__ counts) {
    int e = blockIdx.x * blockDim.x + threadIdx.x;
    if (e >= GETOT) return;
    int d;
    if (e < GE) d = load_idx(ei, *flagp, (long long)GE + e);
    else        d = e - GE;                    // self loop
    atomicAdd(&counts[d], 1);
}

__global__ void scan_kernel(const int* __restrict__ counts, int* __restrict__ offsets,
                            int* __restrict__ cursor) {
    __shared__ int sh[1024];
    int tid = threadIdx.x;
    int carry = 0;
    for (int base = 0; base < GN; base += 1024) {
        int i = base + tid;
        int v = (i < GN) ? counts[i] : 0;
        sh[tid] = v;
        __syncthreads();
        for (int o = 1; o < 1024; o <<= 1) {
            int t = (tid >= o) ? sh[tid - o] : 0;
            __syncthreads();
            sh[tid] += t;
            __syncthreads();
        }
        int excl = carry + sh[tid] - v;
        if (i < GN) { offsets[i] = excl; cursor[i] = excl; }
        carry += sh[1023];
        __syncthreads();
    }
    if (tid == 0) offsets[GN] = carry;
}

__global__ void scatter_kernel(const void* __restrict__ ei, const int* __restrict__ flagp,
                               int* __restrict__ cursor, int* __restrict__ csr_src) {
    int e = blockIdx.x * blockDim.x + threadIdx.x;
    if (e >= GETOT) return;
    int s, d;
    if (e < GE) {
        int is64 = *flagp;
        s = load_idx(ei, is64, e);
        d = load_idx(ei, is64, (long long)GE + e);
    } else {
        s = d = e - GE;
    }
    int pos = atomicAdd(&cursor[d], 1);
    csr_src[pos] = s;
}

// ---------------------------------------------------------------------------
// fp32 GEMM: C[M,N] = A[M,K] @ B[K,N].  128x128 tile, BK=16, 8x8 micro-tile.
// K and N must be multiples of 16 / 128 respectively (true for all layers).
// ---------------------------------------------------------------------------
__global__ __launch_bounds__(256) void gemm_nn(const float* __restrict__ A,
                                               const float* __restrict__ B,
                                               float* __restrict__ C,
                                               int M, int K, int Nn) {
    __shared__ float As[16][132];
    __shared__ float Bs[16][132];
    const int tid = threadIdx.x;
    const int bm = blockIdx.y * 128;
    const int bn = blockIdx.x * 128;

    const int rowA = tid >> 2;            // 0..63
    const int kq   = (tid & 3) << 2;      // 0,4,8,12
    const int krB  = tid >> 5;            // 0..7
    const int nq   = (tid & 31) << 2;     // 0..124
    const int ty   = tid >> 4;            // 0..15
    const int tx   = tid & 15;            // 0..15

    float acc[8][8];
#pragma unroll
    for (int i = 0; i < 8; ++i)
#pragma unroll
        for (int j = 0; j < 8; ++j) acc[i][j] = 0.f;

    const int r0 = bm + rowA, r1 = bm + rowA + 64;
    const bool v0 = r0 < M, v1 = r1 < M;
    const float* A0 = A + (size_t)r0 * K + kq;
    const float* A1 = A + (size_t)r1 * K + kq;
    const float* Bp = B + (size_t)krB * Nn + bn + nq;

    for (int k0 = 0; k0 < K; k0 += 16) {
        float4 a0 = make_float4(0.f, 0.f, 0.f, 0.f);
        float4 a1 = make_float4(0.f, 0.f, 0.f, 0.f);
        if (v0) a0 = *(const float4*)(A0 + k0);
        if (v1) a1 = *(const float4*)(A1 + k0);
        float4 b0 = *(const float4*)(Bp + (size_t)k0 * Nn);
        float4 b1 = *(const float4*)(Bp + (size_t)(k0 + 8) * Nn);
        __syncthreads();
        As[kq + 0][rowA] = a0.x; As[kq + 1][rowA] = a0.y;
        As[kq + 2][rowA] = a0.z; As[kq + 3][rowA] = a0.w;
        As[kq + 0][rowA + 64] = a1.x; As[kq + 1][rowA + 64] = a1.y;
        As[kq + 2][rowA + 64] = a1.z; As[kq + 3][rowA + 64] = a1.w;
        *(float4*)&Bs[krB][nq]     = b0;
        *(float4*)&Bs[krB + 8][nq] = b1;
        __syncthreads();
#pragma unroll
        for (int k = 0; k < 16; ++k) {
            float4 aA = *(const float4*)&As[k][ty << 2];
            float4 aB = *(const float4*)&As[k][64 + (ty << 2)];
            float4 bA = *(const float4*)&Bs[k][tx << 2];
            float4 bB = *(const float4*)&Bs[k][64 + (tx << 2)];
            float ar[8] = {aA.x, aA.y, aA.z, aA.w, aB.x, aB.y, aB.z, aB.w};
            float br[8] = {bA.x, bA.y, bA.z, bA.w, bB.x, bB.y, bB.z, bB.w};
#pragma unroll
            for (int i = 0; i < 8; ++i)
#pragma unroll
                for (int j = 0; j < 8; ++j)
                    acc[i][j] = fmaf(ar[i], br[j], acc[i][j]);
        }
    }

#pragma unroll
    for (int i = 0; i < 8; ++i) {
        int m = bm + ((i < 4) ? (ty * 4 + i) : (64 + ty * 4 + i - 4));
        if (m < M) {
            float* Cr = C + (size_t)m * Nn + bn;
            *(float4*)(Cr + tx * 4)      = make_float4(acc[i][0], acc[i][1], acc[i][2], acc[i][3]);
            *(float4*)(Cr + 64 + tx * 4) = make_float4(acc[i][4], acc[i][5], acc[i][6], acc[i][7]);
        }
    }
}

// ---------------------------------------------------------------------------
// a_s[n,h] = dot(h[n,h,:], att_src[h,:]);  a_d likewise.  One wave per node.
// ---------------------------------------------------------------------------
__global__ void att_sd_kernel(const float* __restrict__ hfeat,
                              const float* __restrict__ att_s,
                              const float* __restrict__ att_d,
                              float* __restrict__ a_s, float* __restrict__ a_d,
                              int C) {
    int wid  = (blockIdx.x * blockDim.x + threadIdx.x) >> 6;
    int lane = threadIdx.x & 63;
    if (wid >= GN) return;
#pragma unroll
    for (int h = 0; h < GH; ++h) {
        float ss = 0.f, sd = 0.f;
        for (int cc = lane; cc < C; cc += 64) {
            float v = hfeat[(size_t)wid * GH * C + h * C + cc];
            ss += v * att_s[h * C + cc];
            sd += v * att_d[h * C + cc];
        }
#pragma unroll
        for (int o = 32; o; o >>= 1) {
            ss += __shfl_xor(ss, o);
            sd += __shfl_xor(sd, o);
        }
        if (lane == 0) { a_s[wid * GH + h] = ss; a_d[wid * GH + h] = sd; }
    }
}

// ---------------------------------------------------------------------------
// Per-node softmax + weighted aggregation.  Block (256 threads) per node.
// Phase A (wave 0): per-head max & exp-sum over incident edges.
// Phase B (all):   per-channel accumulation of alpha * h[src].
// ---------------------------------------------------------------------------
template <int C, bool CONCAT, bool ELU>
__global__ __launch_bounds__(256) void gat_aggregate(
        const float* __restrict__ hfeat,
        const float* __restrict__ a_s,
        const float* __restrict__ a_d,
        const int* __restrict__ offsets,
        const int* __restrict__ csr_src,
        const float* __restrict__ bias,
        float* __restrict__ out) {
    constexpr int HC  = GH * C;
    constexpr int CPT = (HC + 255) / 256;
    const int n   = blockIdx.x;
    const int tid = threadIdx.x;
    const int start = offsets[n];
    const int end   = offsets[n + 1];

    __shared__ float s_m[GH];
    __shared__ float s_den[GH];
    __shared__ float sacc[256];

    if (tid < 64) {
        float ad[GH], lmax[GH], lsum[GH];
#pragma unroll
        for (int h = 0; h < GH; ++h) { ad[h] = a_d[n * GH + h]; lmax[h] = -1e30f; }
        for (int e = start + tid; e < end; e += 64) {
            int s = csr_src[e];
#pragma unroll
            for (int h = 0; h < GH; ++h) {
                float l = a_s[s * GH + h] + ad[h];
                l = l > 0.f ? l : 0.2f * l;
                lmax[h] = fmaxf(lmax[h], l);
            }
        }
#pragma unroll
        for (int h = 0; h < GH; ++h)
#pragma unroll
            for (int o = 32; o; o >>= 1) lmax[h] = fmaxf(lmax[h], __shfl_xor(lmax[h], o));
#pragma unroll
        for (int h = 0; h < GH; ++h) lsum[h] = 0.f;
        for (int e = start + tid; e < end; e += 64) {
            int s = csr_src[e];
#pragma unroll
            for (int h = 0; h < GH; ++h) {
                float l = a_s[s * GH + h] + ad[h];
                l = l > 0.f ? l : 0.2f * l;
                lsum[h] += __expf(l - lmax[h]);
            }
        }
#pragma unroll
        for (int h = 0; h < GH; ++h)
#pragma unroll
            for (int o = 32; o; o >>= 1) lsum[h] += __shfl_xor(lsum[h], o);
        if (tid == 0) {
#pragma unroll
            for (int h = 0; h < GH; ++h) { s_m[h] = lmax[h]; s_den[h] = lsum[h]; }
        }
    }
    __syncthreads();

    float acc[CPT];
    int   head[CPT];
    float adh[CPT], mh[CPT], inv[CPT];
#pragma unroll
    for (int i = 0; i < CPT; ++i) {
        int ch = tid + i * 256;
        acc[i] = 0.f;
        if (ch < HC) {
            head[i] = ch / C;
            adh[i]  = a_d[n * GH + head[i]];
            mh[i]   = s_m[head[i]];
            inv[i]  = 1.0f / s_den[head[i]];
        } else {
            head[i] = 0; adh[i] = 0.f; mh[i] = 0.f; inv[i] = 0.f;
        }
    }

    for (int e = start; e < end; ++e) {
        int s = csr_src[e];
#pragma unroll
        for (int i = 0; i < CPT; ++i) {
            int ch = tid + i * 256;
            if (ch < HC) {
                float l = a_s[s * GH + head[i]] + adh[i];
                l = l > 0.f ? l : 0.2f * l;
                float alpha = __expf(l - mh[i]) * inv[i];
                acc[i] = fmaf(alpha, hfeat[(size_t)s * HC + ch], acc[i]);
            }
        }
    }

    if (CONCAT) {
#pragma unroll
        for (int i = 0; i < CPT; ++i) {
            int ch = tid + i * 256;
            if (ch < HC) {
                float v = acc[i] + bias[ch];
                if (ELU) v = v > 0.f ? v : expm1f(v);
                out[(size_t)n * HC + ch] = v;
            }
        }
    } else {
        // mean over heads (HC <= 256 guaranteed for the final layer)
#pragma unroll
        for (int i = 0; i < CPT; ++i) {
            int ch = tid + i * 256;
            if (ch < HC) sacc[ch] = acc[i];
        }
        __syncthreads();
        if (tid < C) {
            float v = 0.f;
#pragma unroll
            for (int h = 0; h < GH; ++h) v += sacc[h * C + tid];
            v = v * (1.0f / GH) + bias[tid];
            out[(size_t)n * C + tid] = v;
        }
    }
}

// ---------------------------------------------------------------------------
extern "C" void kernel_launch(void* const* d_in, const int* in_sizes, int n_in,
                              void* d_out, int out_size, void* d_ws, size_t ws_size,
                              hipStream_t stream) {
    const float* x  = (const float*)d_in[0];
    const void*  ei = d_in[1];
    const float* W[4]  = {(const float*)d_in[2],  (const float*)d_in[6],
                          (const float*)d_in[10], (const float*)d_in[14]};
    const float* AS[4] = {(const float*)d_in[3],  (const float*)d_in[7],
                          (const float*)d_in[11], (const float*)d_in[15]};
    const float* AD[4] = {(const float*)d_in[4],  (const float*)d_in[8],
                          (const float*)d_in[12], (const float*)d_in[16]};
    const float* BI[4] = {(const float*)d_in[5],  (const float*)d_in[9],
                          (const float*)d_in[13], (const float*)d_in[17]};

    // workspace carve-up (256B aligned)
    char*  w   = (char*)d_ws;
    size_t off = 0;
    auto alloc = [&](size_t b) -> char* {
        char* p = w + off;
        off += (b + 255) & ~(size_t)255;
        return p;
    };
    int*   flag    = (int*)alloc(4);
    int*   counts  = (int*)alloc((GN + 1) * sizeof(int));
    int*   offsets = (int*)alloc((GN + 1) * sizeof(int));
    int*   cursor  = (int*)alloc(GN * sizeof(int));
    int*   csr_src = (int*)alloc((size_t)GETOT * sizeof(int));
    float* a_s     = (float*)alloc((size_t)GN * GH * sizeof(float));
    float* a_d     = (float*)alloc((size_t)GN * GH * sizeof(float));
    float* hbuf    = (float*)alloc((size_t)GN * 512 * sizeof(float));
    float* obuf    = (float*)alloc((size_t)GN * 512 * sizeof(float));
    (void)in_sizes; (void)n_in; (void)out_size; (void)ws_size;

    // ---- build CSR by destination (graph identical for all layers) ----
    detect_dtype_kernel<<<1, 64, 0, stream>>>(ei, flag);
    hipMemsetAsync(counts, 0, (GN + 1) * sizeof(int), stream);
    int eblocks = (GETOT + 255) / 256;
    hist_kernel<<<eblocks, 256, 0, stream>>>(ei, flag, counts);
    scan_kernel<<<1, 1024, 0, stream>>>(counts, offsets, cursor);
    scatter_kernel<<<eblocks, 256, 0, stream>>>(ei, flag, cursor, csr_src);

    const int M = GN;
    // ---- layer 0: 2000 -> 4x128 concat, ELU ----
    {
        dim3 grid(512 / 128, (M + 127) / 128);
        gemm_nn<<<grid, 256, 0, stream>>>(x, W[0], hbuf, M, 2000, 512);
        att_sd_kernel<<<(GN * 64) / 256, 256, 0, stream>>>(hbuf, AS[0], AD[0], a_s, a_d, 128);
        gat_aggregate<128, true, true><<<GN, 256, 0, stream>>>(hbuf, a_s, a_d, offsets, csr_src, BI[0], obuf);
    }
    // ---- layer 1: 512 -> 4x64 concat, ELU ----
    {
        dim3 grid(256 / 128, (M + 127) / 128);
        gemm_nn<<<grid, 256, 0, stream>>>(obuf, W[1], hbuf, M, 512, 256);
        att_sd_kernel<<<(GN * 64) / 256, 256, 0, stream>>>(hbuf, AS[1], AD[1], a_s, a_d, 64);
        gat_aggregate<64, true, true><<<GN, 256, 0, stream>>>(hbuf, a_s, a_d, offsets, csr_src, BI[1], obuf);
    }
    // ---- layer 2: 256 -> 4x32 concat, ELU ----
    {
        dim3 grid(128 / 128, (M + 127) / 128);
        gemm_nn<<<grid, 256, 0, stream>>>(obuf, W[2], hbuf, M, 256, 128);
        att_sd_kernel<<<(GN * 64) / 256, 256, 0, stream>>>(hbuf, AS[2], AD[2], a_s, a_d, 32);
        gat_aggregate<32, true, true><<<GN, 256, 0, stream>>>(hbuf, a_s, a_d, offsets, csr_src, BI[2], obuf);
    }
    // ---- layer 3: 128 -> 4x64 mean, no ELU ----
    {
        dim3 grid(256 / 128, (M + 127) / 128);
        gemm_nn<<<grid, 256, 0, stream>>>(obuf, W[3], hbuf, M, 128, 256);
        att_sd_kernel<<<(GN * 64) / 256, 256, 0, stream>>>(hbuf, AS[3], AD[3], a_s, a_d, 64);
        gat_aggregate<64, false, false><<<GN, 256, 0, stream>>>(hbuf, a_s, a_d, offsets, csr_src, BI[3], (float*)d_out);
    }
}

// Round 2
// 1011.136 us; speedup vs baseline: 1.3044x; 1.3044x over previous
//
#include <hip/hip_runtime.h>
#include <hip/hip_bf16.h>

#define GN 20000          // nodes
#define GE 320000         // edges (without self loops)
#define GETOT (GE + GN)   // edges + self loops
#define GH 4              // heads

typedef __attribute__((ext_vector_type(8))) short bf16x8;   // 8 bf16 = 4 VGPR
typedef __attribute__((ext_vector_type(4))) float f32x4;

// ---------------------------------------------------------------------------
// edge_index dtype detection (int64 vs x64-disabled int32)
// ---------------------------------------------------------------------------
__global__ void detect_dtype_kernel(const void* __restrict__ ei, int* __restrict__ flag) {
    if (threadIdx.x == 0 && blockIdx.x == 0) {
        const long long* p = (const long long*)ei;
        int ok = 1;
        for (int i = 0; i < 16; ++i) {
            long long v = p[i];
            if (v < 0 || v >= GN) ok = 0;
        }
        *flag = ok;
    }
}

__device__ __forceinline__ int load_idx(const void* ei, int is64, long long pos) {
    if (is64) return (int)((const long long*)ei)[pos];
    return ((const int*)ei)[pos];
}

// ---------------------------------------------------------------------------
// CSR build
// ---------------------------------------------------------------------------
__global__ void hist_kernel(const void* __restrict__ ei, const int* __restrict__ flagp,
                            int* __restrict__ counts) {
    int e = blockIdx.x * blockDim.x + threadIdx.x;
    if (e >= GETOT) return;
    int d;
    if (e < GE) d = load_idx(ei, *flagp, (long long)GE + e);
    else        d = e - GE;
    atomicAdd(&counts[d], 1);
}

__global__ void scan_kernel(const int* __restrict__ counts, int* __restrict__ offsets,
                            int* __restrict__ cursor) {
    __shared__ int sh[1024];
    int tid = threadIdx.x;
    int carry = 0;
    for (int base = 0; base < GN; base += 1024) {
        int i = base + tid;
        int v = (i < GN) ? counts[i] : 0;
        sh[tid] = v;
        __syncthreads();
        for (int o = 1; o < 1024; o <<= 1) {
            int t = (tid >= o) ? sh[tid - o] : 0;
            __syncthreads();
            sh[tid] += t;
            __syncthreads();
        }
        int excl = carry + sh[tid] - v;
        if (i < GN) { offsets[i] = excl; cursor[i] = excl; }
        carry += sh[1023];
        __syncthreads();
    }
    if (tid == 0) offsets[GN] = carry;
}

__global__ void scatter_kernel(const void* __restrict__ ei, const int* __restrict__ flagp,
                               int* __restrict__ cursor, int* __restrict__ csr_src) {
    int e = blockIdx.x * blockDim.x + threadIdx.x;
    if (e >= GETOT) return;
    int s, d;
    if (e < GE) {
        int is64 = *flagp;
        s = load_idx(ei, is64, e);
        d = load_idx(ei, is64, (long long)GE + e);
    } else {
        s = d = e - GE;
    }
    int pos = atomicAdd(&cursor[d], 1);
    csr_src[pos] = s;
}

// ---------------------------------------------------------------------------
// hi/lo bf16 split helpers
// ---------------------------------------------------------------------------
__device__ __forceinline__ void split_bf16(float v, __hip_bfloat16& h, __hip_bfloat16& l) {
    __hip_bfloat16 hh = __float2bfloat16(v);
    float r = v - __bfloat162float(hh);
    h = hh;
    l = __float2bfloat16(r);
}

// convert one K-chunk of x (fp32 [GN][2000]) into hi/lo bf16 [GN][512], zero-pad
__global__ void convert_x_chunk(const float* __restrict__ x,
                                __hip_bfloat16* __restrict__ hi,
                                __hip_bfloat16* __restrict__ lo, int c0) {
    int idx = blockIdx.x * 256 + threadIdx.x;     // one thread = 4 elements
    if (idx >= GN * 128) return;
    int row = idx >> 7;
    int g   = idx & 127;
    int col = c0 + g * 4;
    float4 v = make_float4(0.f, 0.f, 0.f, 0.f);
    if (col + 3 < 2000) v = *(const float4*)(x + (size_t)row * 2000 + col);
    __hip_bfloat16 h0, l0, h1, l1, h2, l2, h3, l3;
    split_bf16(v.x, h0, l0); split_bf16(v.y, h1, l1);
    split_bf16(v.z, h2, l2); split_bf16(v.w, h3, l3);
    size_t o = (size_t)row * 512 + g * 4;
    hi[o + 0] = h0; hi[o + 1] = h1; hi[o + 2] = h2; hi[o + 3] = h3;
    lo[o + 0] = l0; lo[o + 1] = l1; lo[o + 2] = l2; lo[o + 3] = l3;
}

// W fp32 [K][N]  ->  Wt hi/lo bf16 [N][Kpad] (transposed, zero-padded K)
__global__ void convert_wt(const float* __restrict__ W,
                           __hip_bfloat16* __restrict__ thi,
                           __hip_bfloat16* __restrict__ tlo,
                           int K, int N, int Kpad) {
    __shared__ float tile[32][33];
    int kb = blockIdx.x * 32, nb = blockIdx.y * 32;
    for (int i = threadIdx.y; i < 32; i += 8) {
        int k = kb + i, n = nb + threadIdx.x;
        tile[i][threadIdx.x] = (k < K) ? W[(size_t)k * N + n] : 0.f;
    }
    __syncthreads();
    for (int i = threadIdx.y; i < 32; i += 8) {
        int n = nb + i, k = kb + threadIdx.x;
        float v = tile[threadIdx.x][i];
        __hip_bfloat16 h, l;
        split_bf16(v, h, l);
        thi[(size_t)n * Kpad + k] = h;
        tlo[(size_t)n * Kpad + k] = l;
    }
}

// ---------------------------------------------------------------------------
// MFMA GEMM:  C[M,N] (+)= Ahi*Bhi + Ahi*Blo + Alo*Bhi
// A: [M][lda] bf16 row-major (K-contiguous). B: [N][ldb] bf16 (W^T, K-contig).
// 128x128 tile, BK=32, 4 waves, mfma_f32_16x16x32_bf16.
// LDS XOR swizzle: phys = a ^ (((a>>6)&7)<<4); staging uses inverse on source.
// ---------------------------------------------------------------------------
__device__ __forceinline__ int swz(int a) { return a ^ (((a >> 6) & 7) << 4); }
__device__ __forceinline__ int invswz(int p) {
    int b8 = (p >> 8) & 1, b7 = (p >> 7) & 1;
    int a6 = ((p >> 6) & 1) ^ b8;
    int a5 = ((p >> 5) & 1) ^ b7;
    int a4 = ((p >> 4) & 1) ^ a6;
    return (p & ~0x70) | (a4 << 4) | (a5 << 5) | (a6 << 6);
}

#define GLDS16(gsrc, ldst) __builtin_amdgcn_global_load_lds( \
    (const __attribute__((address_space(1))) void*)(gsrc),   \
    (__attribute__((address_space(3))) void*)(ldst), 16, 0, 0)

template <bool ACCUM>
__global__ __launch_bounds__(256) void gemm_mfma(
        const __hip_bfloat16* __restrict__ Ahi, const __hip_bfloat16* __restrict__ Alo, int lda,
        const __hip_bfloat16* __restrict__ Bhi, const __hip_bfloat16* __restrict__ Blo, int ldb,
        int kb0, float* __restrict__ C, int M, int N, int Ksz) {
    __shared__ char Ah_s[8192];
    __shared__ char Al_s[8192];
    __shared__ char Bh_s[8192];
    __shared__ char Bl_s[8192];
    const int tid  = threadIdx.x;
    const int brow = blockIdx.y * 128;
    const int bcol = blockIdx.x * 128;
    const int lane = tid & 63;
    const int wid  = tid >> 6;
    const int wr   = wid >> 1, wc = wid & 1;

    // staging map: physical dest p = pass*4096 + tid*16 ; logical = invswz(p)
    int sdst[2], srowA[2], srowB[2], skel[2];
    for (int pass = 0; pass < 2; ++pass) {
        int p = pass * 4096 + tid * 16;
        int a = invswz(p);
        sdst[pass] = p;
        int r = a >> 6;
        skel[pass] = (a & 63) >> 1;        // bf16 element offset within row
        int rg = brow + r;
        srowA[pass] = rg < M ? rg : (M - 1);
        srowB[pass] = bcol + r;            // N multiple of 128 -> always valid
    }

    // fragment read offsets (swizzled), same for hi/lo tiles
    const int l4 = lane & 15, kg = lane >> 4;
    int aoff[4], boff[4];
#pragma unroll
    for (int m = 0; m < 4; ++m) {
        aoff[m] = swz((wr * 64 + m * 16 + l4) * 64 + kg * 16);
        boff[m] = swz((wc * 64 + m * 16 + l4) * 64 + kg * 16);
    }

    f32x4 acc[4][4];
#pragma unroll
    for (int m = 0; m < 4; ++m)
#pragma unroll
        for (int n = 0; n < 4; ++n) acc[m][n] = (f32x4)(0.f);

    for (int k0 = 0; k0 < Ksz; k0 += 32) {
        __syncthreads();
#pragma unroll
        for (int pass = 0; pass < 2; ++pass) {
            size_t ao = (size_t)srowA[pass] * lda + k0 + skel[pass];
            GLDS16(Ahi + ao, Ah_s + sdst[pass]);
            GLDS16(Alo + ao, Al_s + sdst[pass]);
            size_t bo = (size_t)srowB[pass] * ldb + kb0 + k0 + skel[pass];
            GLDS16(Bhi + bo, Bh_s + sdst[pass]);
            GLDS16(Blo + bo, Bl_s + sdst[pass]);
        }
        __syncthreads();

        bf16x8 ah[4], al[4], bh[4], bl[4];
#pragma unroll
        for (int m = 0; m < 4; ++m) {
            ah[m] = *(const bf16x8*)(Ah_s + aoff[m]);
            al[m] = *(const bf16x8*)(Al_s + aoff[m]);
        }
#pragma unroll
        for (int n = 0; n < 4; ++n) {
            bh[n] = *(const bf16x8*)(Bh_s + boff[n]);
            bl[n] = *(const bf16x8*)(Bl_s + boff[n]);
        }
#pragma unroll
        for (int m = 0; m < 4; ++m)
#pragma unroll
            for (int n = 0; n < 4; ++n) {
                acc[m][n] = __builtin_amdgcn_mfma_f32_16x16x32_bf16(ah[m], bh[n], acc[m][n], 0, 0, 0);
                acc[m][n] = __builtin_amdgcn_mfma_f32_16x16x32_bf16(ah[m], bl[n], acc[m][n], 0, 0, 0);
                acc[m][n] = __builtin_amdgcn_mfma_f32_16x16x32_bf16(al[m], bh[n], acc[m][n], 0, 0, 0);
            }
    }

    // epilogue: D col = lane&15, row = (lane>>4)*4 + r   [m89/m91 verified]
#pragma unroll
    for (int m = 0; m < 4; ++m) {
        int gr0 = brow + wr * 64 + m * 16 + (lane >> 4) * 4;
#pragma unroll
        for (int n = 0; n < 4; ++n) {
            int gc = bcol + wc * 64 + n * 16 + (lane & 15);
#pragma unroll
            for (int r = 0; r < 4; ++r) {
                int gr = gr0 + r;
                if (gr < M) {
                    size_t o = (size_t)gr * N + gc;
                    float v = acc[m][n][r];
                    if (ACCUM) v += C[o];
                    C[o] = v;
                }
            }
        }
    }
}

// ---------------------------------------------------------------------------
// a_s / a_d per-node logits
// ---------------------------------------------------------------------------
__global__ void att_sd_kernel(const float* __restrict__ hfeat,
                              const float* __restrict__ att_s,
                              const float* __restrict__ att_d,
                              float* __restrict__ a_s, float* __restrict__ a_d,
                              int C) {
    int wid  = (blockIdx.x * blockDim.x + threadIdx.x) >> 6;
    int lane = threadIdx.x & 63;
    if (wid >= GN) return;
#pragma unroll
    for (int h = 0; h < GH; ++h) {
        float ss = 0.f, sd = 0.f;
        for (int cc = lane; cc < C; cc += 64) {
            float v = hfeat[(size_t)wid * GH * C + h * C + cc];
            ss += v * att_s[h * C + cc];
            sd += v * att_d[h * C + cc];
        }
#pragma unroll
        for (int o = 32; o; o >>= 1) {
            ss += __shfl_xor(ss, o);
            sd += __shfl_xor(sd, o);
        }
        if (lane == 0) { a_s[wid * GH + h] = ss; a_d[wid * GH + h] = sd; }
    }
}

// ---------------------------------------------------------------------------
// Per-node softmax + aggregation. Alpha precomputed per (edge,head) in LDS.
// FINAL=false: concat + ELU, write bf16 hi/lo activations for next GEMM.
// FINAL=true : head-mean + bias -> fp32 d_out.
// ---------------------------------------------------------------------------
template <int C, bool FINAL>
__global__ __launch_bounds__(256) void gat_aggregate(
        const float* __restrict__ hfeat,
        const float* __restrict__ a_s,
        const float* __restrict__ a_d,
        const int* __restrict__ offsets,
        const int* __restrict__ csr_src,
        const float* __restrict__ bias,
        __hip_bfloat16* __restrict__ ohi,
        __hip_bfloat16* __restrict__ olo,
        float* __restrict__ outf) {
    constexpr int HC  = GH * C;
    constexpr int CPT = (HC + 255) / 256;
    const int n     = blockIdx.x;
    const int tid   = threadIdx.x;
    const int start = offsets[n];
    const int end   = offsets[n + 1];

    __shared__ float s_m[GH];
    __shared__ float s_den[GH];
    __shared__ float s_alpha[64 * GH];
    __shared__ int   s_srcid[64];
    __shared__ float sacc[256];

    const float4 ad4 = *(const float4*)(a_d + n * GH);
    const float adh[GH] = {ad4.x, ad4.y, ad4.z, ad4.w};

    if (tid < 64) {
        float lmax[GH], lsum[GH];
#pragma unroll
        for (int h = 0; h < GH; ++h) lmax[h] = -1e30f;
        for (int e = start + tid; e < end; e += 64) {
            int s = csr_src[e];
            float4 as4 = *(const float4*)(a_s + s * GH);
            float l0 = as4.x + adh[0], l1 = as4.y + adh[1];
            float l2 = as4.z + adh[2], l3 = as4.w + adh[3];
            l0 = l0 > 0.f ? l0 : 0.2f * l0; l1 = l1 > 0.f ? l1 : 0.2f * l1;
            l2 = l2 > 0.f ? l2 : 0.2f * l2; l3 = l3 > 0.f ? l3 : 0.2f * l3;
            lmax[0] = fmaxf(lmax[0], l0); lmax[1] = fmaxf(lmax[1], l1);
            lmax[2] = fmaxf(lmax[2], l2); lmax[3] = fmaxf(lmax[3], l3);
        }
#pragma unroll
        for (int h = 0; h < GH; ++h)
#pragma unroll
            for (int o = 32; o; o >>= 1) lmax[h] = fmaxf(lmax[h], __shfl_xor(lmax[h], o));
#pragma unroll
        for (int h = 0; h < GH; ++h) lsum[h] = 0.f;
        for (int e = start + tid; e < end; e += 64) {
            int s = csr_src[e];
            float4 as4 = *(const float4*)(a_s + s * GH);
            float l[GH] = {as4.x + adh[0], as4.y + adh[1], as4.z + adh[2], as4.w + adh[3]};
#pragma unroll
            for (int h = 0; h < GH; ++h) {
                float ll = l[h] > 0.f ? l[h] : 0.2f * l[h];
                lsum[h] += __expf(ll - lmax[h]);
            }
        }
#pragma unroll
        for (int h = 0; h < GH; ++h)
#pragma unroll
            for (int o = 32; o; o >>= 1) lsum[h] += __shfl_xor(lsum[h], o);
        if (tid == 0) {
#pragma unroll
            for (int h = 0; h < GH; ++h) { s_m[h] = lmax[h]; s_den[h] = lsum[h]; }
        }
    }
    __syncthreads();

    float mm[GH], inv[GH];
#pragma unroll
    for (int h = 0; h < GH; ++h) { mm[h] = s_m[h]; inv[h] = 1.0f / s_den[h]; }

    float acc[CPT];
    int   head[CPT];
#pragma unroll
    for (int i = 0; i < CPT; ++i) {
        int ch = tid + i * 256;
        acc[i]  = 0.f;
        head[i] = (ch < HC) ? (ch / C) : 0;
    }

    for (int e0 = start; e0 < end; e0 += 64) {
        int cnt = min(64, end - e0);
        __syncthreads();
        if (tid < cnt) {
            int s = csr_src[e0 + tid];
            s_srcid[tid] = s;
            float4 as4 = *(const float4*)(a_s + s * GH);
            float l[GH] = {as4.x + adh[0], as4.y + adh[1], as4.z + adh[2], as4.w + adh[3]};
#pragma unroll
            for (int h = 0; h < GH; ++h) {
                float ll = l[h] > 0.f ? l[h] : 0.2f * l[h];
                s_alpha[tid * GH + h] = __expf(ll - mm[h]) * inv[h];
            }
        }
        __syncthreads();
        for (int i = 0; i < cnt; ++i) {
            int s = s_srcid[i];
            const float* hp = hfeat + (size_t)s * HC;
#pragma unroll
            for (int j = 0; j < CPT; ++j) {
                int ch = tid + j * 256;
                if (ch < HC) acc[j] = fmaf(s_alpha[i * GH + head[j]], hp[ch], acc[j]);
            }
        }
    }

    if (!FINAL) {
#pragma unroll
        for (int j = 0; j < CPT; ++j) {
            int ch = tid + j * 256;
            if (ch < HC) {
                float v = acc[j] + bias[ch];
                v = v > 0.f ? v : expm1f(v);
                __hip_bfloat16 h, l;
                split_bf16(v, h, l);
                ohi[(size_t)n * HC + ch] = h;
                olo[(size_t)n * HC + ch] = l;
            }
        }
    } else {
#pragma unroll
        for (int j = 0; j < CPT; ++j) {
            int ch = tid + j * 256;
            if (ch < HC) sacc[ch] = acc[j];
        }
        __syncthreads();
        if (tid < C) {
            float v = 0.f;
#pragma unroll
            for (int h = 0; h < GH; ++h) v += sacc[h * C + tid];
            outf[(size_t)n * C + tid] = v * (1.0f / GH) + bias[tid];
        }
    }
}

// ---------------------------------------------------------------------------
extern "C" void kernel_launch(void* const* d_in, const int* in_sizes, int n_in,
                              void* d_out, int out_size, void* d_ws, size_t ws_size,
                              hipStream_t stream) {
    const float* x  = (const float*)d_in[0];
    const void*  ei = d_in[1];
    const float* W[4]  = {(const float*)d_in[2],  (const float*)d_in[6],
                          (const float*)d_in[10], (const float*)d_in[14]};
    const float* AS[4] = {(const float*)d_in[3],  (const float*)d_in[7],
                          (const float*)d_in[11], (const float*)d_in[15]};
    const float* AD[4] = {(const float*)d_in[4],  (const float*)d_in[8],
                          (const float*)d_in[12], (const float*)d_in[16]};
    const float* BI[4] = {(const float*)d_in[5],  (const float*)d_in[9],
                          (const float*)d_in[13], (const float*)d_in[17]};

    char*  w   = (char*)d_ws;
    size_t off = 0;
    auto alloc = [&](size_t b) -> char* {
        char* p = w + off;
        off += (b + 255) & ~(size_t)255;
        return p;
    };
    int*   flag    = (int*)alloc(4);
    int*   counts  = (int*)alloc((GN + 1) * sizeof(int));
    int*   offsets = (int*)alloc((GN + 1) * sizeof(int));
    int*   cursor  = (int*)alloc(GN * sizeof(int));
    int*   csr_src = (int*)alloc((size_t)GETOT * sizeof(int));
    float* a_s     = (float*)alloc((size_t)GN * GH * sizeof(float));
    float* a_d     = (float*)alloc((size_t)GN * GH * sizeof(float));
    float* hbuf    = (float*)alloc((size_t)GN * 512 * sizeof(float));                // 41 MB
    __hip_bfloat16* ohi = (__hip_bfloat16*)alloc((size_t)GN * 512 * 2);              // 20.5 MB
    __hip_bfloat16* olo = (__hip_bfloat16*)alloc((size_t)GN * 512 * 2);              // 20.5 MB
    __hip_bfloat16* wthi = (__hip_bfloat16*)alloc((size_t)512 * 2048 * 2);           // 2 MB
    __hip_bfloat16* wtlo = (__hip_bfloat16*)alloc((size_t)512 * 2048 * 2);           // 2 MB
    (void)in_sizes; (void)n_in; (void)out_size; (void)ws_size;

    // ---- CSR by destination (layer-invariant) ----
    detect_dtype_kernel<<<1, 64, 0, stream>>>(ei, flag);
    hipMemsetAsync(counts, 0, (GN + 1) * sizeof(int), stream);
    int eblocks = (GETOT + 255) / 256;
    hist_kernel<<<eblocks, 256, 0, stream>>>(ei, flag, counts);
    scan_kernel<<<1, 1024, 0, stream>>>(counts, offsets, cursor);
    scatter_kernel<<<eblocks, 256, 0, stream>>>(ei, flag, cursor, csr_src);

    const dim3 tb(32, 8);
    // ---- layer 0: 2000 -> 4x128 concat, ELU.  K chunked 4x512 (ws limit) ----
    {
        convert_wt<<<dim3(2048 / 32, 512 / 32), tb, 0, stream>>>(W[0], wthi, wtlo, 2000, 512, 2048);
        for (int c = 0; c < 4; ++c) {
            // chunk buffers alias ohi/olo (dead until L0 aggregate)
            convert_x_chunk<<<(GN * 128 + 255) / 256, 256, 0, stream>>>(x, ohi, olo, c * 512);
            dim3 g(512 / 128, (GN + 127) / 128);
            if (c == 0)
                gemm_mfma<false><<<g, 256, 0, stream>>>(ohi, olo, 512, wthi, wtlo, 2048,
                                                        c * 512, hbuf, GN, 512, 512);
            else
                gemm_mfma<true><<<g, 256, 0, stream>>>(ohi, olo, 512, wthi, wtlo, 2048,
                                                       c * 512, hbuf, GN, 512, 512);
        }
        att_sd_kernel<<<(GN * 64) / 256, 256, 0, stream>>>(hbuf, AS[0], AD[0], a_s, a_d, 128);
        gat_aggregate<128, false><<<GN, 256, 0, stream>>>(hbuf, a_s, a_d, offsets, csr_src,
                                                          BI[0], ohi, olo, nullptr);
    }
    // ---- layer 1: 512 -> 4x64 concat, ELU ----
    {
        convert_wt<<<dim3(512 / 32, 256 / 32), tb, 0, stream>>>(W[1], wthi, wtlo, 512, 256, 512);
        dim3 g(256 / 128, (GN + 127) / 128);
        gemm_mfma<false><<<g, 256, 0, stream>>>(ohi, olo, 512, wthi, wtlo, 512, 0,
                                                hbuf, GN, 256, 512);
        att_sd_kernel<<<(GN * 64) / 256, 256, 0, stream>>>(hbuf, AS[1], AD[1], a_s, a_d, 64);
        gat_aggregate<64, false><<<GN, 256, 0, stream>>>(hbuf, a_s, a_d, offsets, csr_src,
                                                         BI[1], ohi, olo, nullptr);
    }
    // ---- layer 2: 256 -> 4x32 concat, ELU ----
    {
        convert_wt<<<dim3(256 / 32, 128 / 32), tb, 0, stream>>>(W[2], wthi, wtlo, 256, 128, 256);
        dim3 g(128 / 128, (GN + 127) / 128);
        gemm_mfma<false><<<g, 256, 0, stream>>>(ohi, olo, 256, wthi, wtlo, 256, 0,
                                                hbuf, GN, 128, 256);
        att_sd_kernel<<<(GN * 64) / 256, 256, 0, stream>>>(hbuf, AS[2], AD[2], a_s, a_d, 32);
        gat_aggregate<32, false><<<GN, 256, 0, stream>>>(hbuf, a_s, a_d, offsets, csr_src,
                                                         BI[2], ohi, olo, nullptr);
    }
    // ---- layer 3: 128 -> 4x64 mean, no ELU ----
    {
        convert_wt<<<dim3(128 / 32, 256 / 32), tb, 0, stream>>>(W[3], wthi, wtlo, 128, 256, 128);
        dim3 g(256 / 128, (GN + 127) / 128);
        gemm_mfma<false><<<g, 256, 0, stream>>>(ohi, olo, 128, wthi, wtlo, 128, 0,
                                                hbuf, GN, 256, 128);
        att_sd_kernel<<<(GN * 64) / 256, 256, 0, stream>>>(hbuf, AS[3], AD[3], a_s, a_d, 64);
        gat_aggregate<64, true><<<GN, 256, 0, stream>>>(hbuf, a_s, a_d, offsets, csr_src,
                                                        BI[3], nullptr, nullptr, (float*)d_out);
    }
}

// Round 3
// 588.188 us; speedup vs baseline: 2.2424x; 1.7191x over previous
//
#include <hip/hip_runtime.h>
#include <hip/hip_bf16.h>

#define GN 20000          // nodes
#define GE 320000         // edges (without self loops)
#define GETOT (GE + GN)   // edges + self loops
#define GH 4              // heads

typedef __attribute__((ext_vector_type(8))) short bf16x8;   // 8 bf16 = 4 VGPR
typedef __attribute__((ext_vector_type(4))) short bf16x4;   // 4 bf16 = 2 VGPR
typedef __attribute__((ext_vector_type(4))) float f32x4;

// ---------------------------------------------------------------------------
// edge_index dtype detection (int64 vs x64-disabled int32)
// ---------------------------------------------------------------------------
__global__ void detect_dtype_kernel(const void* __restrict__ ei, int* __restrict__ flag) {
    if (threadIdx.x == 0 && blockIdx.x == 0) {
        const long long* p = (const long long*)ei;
        int ok = 1;
        for (int i = 0; i < 16; ++i) {
            long long v = p[i];
            if (v < 0 || v >= GN) ok = 0;
        }
        *flag = ok;
    }
}

__device__ __forceinline__ int load_idx(const void* ei, int is64, long long pos) {
    if (is64) return (int)((const long long*)ei)[pos];
    return ((const int*)ei)[pos];
}

// ---------------------------------------------------------------------------
// CSR build
// ---------------------------------------------------------------------------
__global__ void hist_kernel(const void* __restrict__ ei, const int* __restrict__ flagp,
                            int* __restrict__ counts) {
    int e = blockIdx.x * blockDim.x + threadIdx.x;
    if (e >= GETOT) return;
    int d;
    if (e < GE) d = load_idx(ei, *flagp, (long long)GE + e);
    else        d = e - GE;
    atomicAdd(&counts[d], 1);
}

__global__ void scan_kernel(const int* __restrict__ counts, int* __restrict__ offsets,
                            int* __restrict__ cursor) {
    __shared__ int sh[1024];
    int tid = threadIdx.x;
    int carry = 0;
    for (int base = 0; base < GN; base += 1024) {
        int i = base + tid;
        int v = (i < GN) ? counts[i] : 0;
        sh[tid] = v;
        __syncthreads();
        for (int o = 1; o < 1024; o <<= 1) {
            int t = (tid >= o) ? sh[tid - o] : 0;
            __syncthreads();
            sh[tid] += t;
            __syncthreads();
        }
        int excl = carry + sh[tid] - v;
        if (i < GN) { offsets[i] = excl; cursor[i] = excl; }
        carry += sh[1023];
        __syncthreads();
    }
    if (tid == 0) offsets[GN] = carry;
}

__global__ void scatter_kernel(const void* __restrict__ ei, const int* __restrict__ flagp,
                               int* __restrict__ cursor, int* __restrict__ csr_src) {
    int e = blockIdx.x * blockDim.x + threadIdx.x;
    if (e >= GETOT) return;
    int s, d;
    if (e < GE) {
        int is64 = *flagp;
        s = load_idx(ei, is64, e);
        d = load_idx(ei, is64, (long long)GE + e);
    } else {
        s = d = e - GE;
    }
    int pos = atomicAdd(&cursor[d], 1);
    csr_src[pos] = s;
}

// ---------------------------------------------------------------------------
// hi/lo bf16 split
// ---------------------------------------------------------------------------
__device__ __forceinline__ void split2(float v, short& h, short& l) {
    __hip_bfloat16 hb = __float2bfloat16(v);
    float r = v - __bfloat162float(hb);
    __hip_bfloat16 lb = __float2bfloat16(r);
    h = *reinterpret_cast<short*>(&hb);
    l = *reinterpret_cast<short*>(&lb);
}

// W fp32 [K][N]  ->  Wt hi/lo bf16 [N][Kpad] (transposed, zero-padded K)
__global__ void convert_wt(const float* __restrict__ W,
                           __hip_bfloat16* __restrict__ thi,
                           __hip_bfloat16* __restrict__ tlo,
                           int K, int N, int Kpad) {
    __shared__ float tile[32][33];
    int kb = blockIdx.x * 32, nb = blockIdx.y * 32;
    for (int i = threadIdx.y; i < 32; i += 8) {
        int k = kb + i, n = nb + threadIdx.x;
        tile[i][threadIdx.x] = (k < K) ? W[(size_t)k * N + n] : 0.f;
    }
    __syncthreads();
    for (int i = threadIdx.y; i < 32; i += 8) {
        int n = nb + i, k = kb + threadIdx.x;
        float v = tile[threadIdx.x][i];
        short h, l;
        split2(v, h, l);
        *(short*)&thi[(size_t)n * Kpad + k] = h;
        *(short*)&tlo[(size_t)n * Kpad + k] = l;
    }
}

// ---------------------------------------------------------------------------
// LDS swizzle (proven round 2): phys = swz(logical); bijective GF(2) map.
// ---------------------------------------------------------------------------
__device__ __forceinline__ int swz(int a) { return a ^ (((a >> 6) & 7) << 4); }
__device__ __forceinline__ int invswz(int p) {
    int b8 = (p >> 8) & 1, b7 = (p >> 7) & 1;
    int a6 = ((p >> 6) & 1) ^ b8;
    int a5 = ((p >> 5) & 1) ^ b7;
    int a4 = ((p >> 4) & 1) ^ a6;
    return (p & ~0x70) | (a4 << 4) | (a5 << 5) | (a6 << 6);
}

#define GLDS16(gsrc, ldst) __builtin_amdgcn_global_load_lds( \
    (const __attribute__((address_space(1))) void*)(gsrc),   \
    (__attribute__((address_space(3))) void*)(ldst), 16, 0, 0)

// ---------------------------------------------------------------------------
// Fused GEMM:  C[M,N] = A_f32[M,K] @ W  via  Ah*Bh + Ah*Bl + Al*Bh
// A staged by registers with on-the-fly hi/lo split (swizzled ds_write).
// B (W^T hi/lo, [N][Kpad] K-contiguous) staged via global_load_lds.
// 128x128 tile, BK=32, 4 waves, mfma_f32_16x16x32_bf16.
// ---------------------------------------------------------------------------
__global__ __launch_bounds__(256) void gemm_fused(
        const float* __restrict__ A, int lda, int K,
        const __hip_bfloat16* __restrict__ Bhi, const __hip_bfloat16* __restrict__ Blo,
        int Kpad, float* __restrict__ C, int M, int N) {
    __shared__ char Ah_s[8192];
    __shared__ char Al_s[8192];
    __shared__ char Bh_s[8192];
    __shared__ char Bl_s[8192];
    const int tid  = threadIdx.x;
    const int brow = blockIdx.y * 128;
    const int bcol = blockIdx.x * 128;
    const int lane = tid & 63;
    const int wid  = tid >> 6;
    const int wr   = wid >> 1, wc = wid & 1;

    // B staging map (global_load_lds): phys p = pass*4096 + tid*16
    int sdst[2], srowB[2], skel[2];
#pragma unroll
    for (int pass = 0; pass < 2; ++pass) {
        int p = pass * 4096 + tid * 16;
        int a = invswz(p);
        sdst[pass] = p;
        skel[pass] = (a & 63) >> 1;        // bf16 elem offset in row
        srowB[pass] = bcol + (a >> 6);     // always valid (N % 128 == 0)
    }

    // A staging map (reg path): unit u = tid + p*256 -> row u>>3, kq (u&7)*4
    int arow[4], acol[4];
#pragma unroll
    for (int p = 0; p < 4; ++p) {
        int u = tid + p * 256;
        arow[p] = u >> 3;
        acol[p] = (u & 7) * 4;
    }

    // fragment read offsets (swizzled)
    const int l4 = lane & 15, kg = lane >> 4;
    int aoff[4], boff[4];
#pragma unroll
    for (int m = 0; m < 4; ++m) {
        aoff[m] = swz((wr * 64 + m * 16 + l4) * 64 + kg * 16);
        boff[m] = swz((wc * 64 + m * 16 + l4) * 64 + kg * 16);
    }

    f32x4 acc[4][4];
#pragma unroll
    for (int m = 0; m < 4; ++m)
#pragma unroll
        for (int n = 0; n < 4; ++n) acc[m][n] = (f32x4)(0.f);

    for (int k0 = 0; k0 < Kpad; k0 += 32) {
        // A global loads (fp32), masked
        float4 av[4];
#pragma unroll
        for (int p = 0; p < 4; ++p) {
            int r = brow + arow[p];
            int kk = k0 + acol[p];
            av[p] = (r < M && kk < K) ? *(const float4*)(A + (size_t)r * lda + kk)
                                      : make_float4(0.f, 0.f, 0.f, 0.f);
        }
        __syncthreads();
        // B async staging
#pragma unroll
        for (int pass = 0; pass < 2; ++pass) {
            size_t bo = (size_t)srowB[pass] * Kpad + k0 + skel[pass];
            GLDS16(Bhi + bo, Bh_s + sdst[pass]);
            GLDS16(Blo + bo, Bl_s + sdst[pass]);
        }
        // A split + swizzled LDS write
#pragma unroll
        for (int p = 0; p < 4; ++p) {
            short h0, l0, h1, l1, h2, l2, h3, l3;
            split2(av[p].x, h0, l0); split2(av[p].y, h1, l1);
            split2(av[p].z, h2, l2); split2(av[p].w, h3, l3);
            bf16x4 hv = {h0, h1, h2, h3};
            bf16x4 lv = {l0, l1, l2, l3};
            int la = swz(arow[p] * 64 + acol[p] * 2);
            *(bf16x4*)(Ah_s + la) = hv;
            *(bf16x4*)(Al_s + la) = lv;
        }
        __syncthreads();

        bf16x8 ah[4], al[4], bh[4], bl[4];
#pragma unroll
        for (int m = 0; m < 4; ++m) {
            ah[m] = *(const bf16x8*)(Ah_s + aoff[m]);
            al[m] = *(const bf16x8*)(Al_s + aoff[m]);
        }
#pragma unroll
        for (int n = 0; n < 4; ++n) {
            bh[n] = *(const bf16x8*)(Bh_s + boff[n]);
            bl[n] = *(const bf16x8*)(Bl_s + boff[n]);
        }
#pragma unroll
        for (int m = 0; m < 4; ++m)
#pragma unroll
            for (int n = 0; n < 4; ++n) {
                acc[m][n] = __builtin_amdgcn_mfma_f32_16x16x32_bf16(ah[m], bh[n], acc[m][n], 0, 0, 0);
                acc[m][n] = __builtin_amdgcn_mfma_f32_16x16x32_bf16(ah[m], bl[n], acc[m][n], 0, 0, 0);
                acc[m][n] = __builtin_amdgcn_mfma_f32_16x16x32_bf16(al[m], bh[n], acc[m][n], 0, 0, 0);
            }
    }

    // epilogue: D col = lane&15, row = (lane>>4)*4 + r
#pragma unroll
    for (int m = 0; m < 4; ++m) {
        int gr0 = brow + wr * 64 + m * 16 + (lane >> 4) * 4;
#pragma unroll
        for (int n = 0; n < 4; ++n) {
            int gc = bcol + wc * 64 + n * 16 + (lane & 15);
#pragma unroll
            for (int r = 0; r < 4; ++r) {
                int gr = gr0 + r;
                if (gr < M) C[(size_t)gr * N + gc] = acc[m][n][r];
            }
        }
    }
}

// ---------------------------------------------------------------------------
// a_s / a_d per-node logits
// ---------------------------------------------------------------------------
__global__ void att_sd_kernel(const float* __restrict__ hfeat,
                              const float* __restrict__ att_s,
                              const float* __restrict__ att_d,
                              float* __restrict__ a_s, float* __restrict__ a_d,
                              int C) {
    int wid  = (blockIdx.x * blockDim.x + threadIdx.x) >> 6;
    int lane = threadIdx.x & 63;
    if (wid >= GN) return;
#pragma unroll
    for (int h = 0; h < GH; ++h) {
        float ss = 0.f, sd = 0.f;
        for (int cc = lane; cc < C; cc += 64) {
            float v = hfeat[(size_t)wid * GH * C + h * C + cc];
            ss += v * att_s[h * C + cc];
            sd += v * att_d[h * C + cc];
        }
#pragma unroll
        for (int o = 32; o; o >>= 1) {
            ss += __shfl_xor(ss, o);
            sd += __shfl_xor(sd, o);
        }
        if (lane == 0) { a_s[wid * GH + h] = ss; a_d[wid * GH + h] = sd; }
    }
}

// ---------------------------------------------------------------------------
// Per-node softmax + aggregation.  BLOCK = HC/2 threads, float2 per thread.
// 4-edge-unrolled gather for memory-level parallelism.
// ---------------------------------------------------------------------------
template <int C, bool FINAL, int BLOCK>
__global__ __launch_bounds__(BLOCK) void gat_aggregate(
        const float* __restrict__ hfeat,
        const float* __restrict__ a_s,
        const float* __restrict__ a_d,
        const int* __restrict__ offsets,
        const int* __restrict__ csr_src,
        const float* __restrict__ bias,
        float* __restrict__ out) {
    constexpr int HC = GH * C;
    static_assert(BLOCK == HC / 2, "one float2 per thread");
    const int n     = blockIdx.x;
    const int tid   = threadIdx.x;
    const int start = offsets[n];
    const int end   = offsets[n + 1];

    __shared__ float s_m[GH];
    __shared__ float s_den[GH];
    __shared__ int   s_src[64];
    __shared__ float s_al[GH][68];
    __shared__ float sacc[256];

    const float4 ad4 = *(const float4*)(a_d + n * GH);
    const float adh[GH] = {ad4.x, ad4.y, ad4.z, ad4.w};

    if (tid < 64) {
        float lmax[GH], lsum[GH];
#pragma unroll
        for (int h = 0; h < GH; ++h) lmax[h] = -1e30f;
        for (int e = start + tid; e < end; e += 64) {
            int s = csr_src[e];
            float4 as4 = *(const float4*)(a_s + s * GH);
            float l[GH] = {as4.x + adh[0], as4.y + adh[1], as4.z + adh[2], as4.w + adh[3]};
#pragma unroll
            for (int h = 0; h < GH; ++h) {
                float ll = l[h] > 0.f ? l[h] : 0.2f * l[h];
                lmax[h] = fmaxf(lmax[h], ll);
            }
        }
#pragma unroll
        for (int h = 0; h < GH; ++h)
#pragma unroll
            for (int o = 32; o; o >>= 1) lmax[h] = fmaxf(lmax[h], __shfl_xor(lmax[h], o));
#pragma unroll
        for (int h = 0; h < GH; ++h) lsum[h] = 0.f;
        for (int e = start + tid; e < end; e += 64) {
            int s = csr_src[e];
            float4 as4 = *(const float4*)(a_s + s * GH);
            float l[GH] = {as4.x + adh[0], as4.y + adh[1], as4.z + adh[2], as4.w + adh[3]};
#pragma unroll
            for (int h = 0; h < GH; ++h) {
                float ll = l[h] > 0.f ? l[h] : 0.2f * l[h];
                lsum[h] += __expf(ll - lmax[h]);
            }
        }
#pragma unroll
        for (int h = 0; h < GH; ++h)
#pragma unroll
            for (int o = 32; o; o >>= 1) lsum[h] += __shfl_xor(lsum[h], o);
        if (tid == 0) {
#pragma unroll
            for (int h = 0; h < GH; ++h) { s_m[h] = lmax[h]; s_den[h] = lsum[h]; }
        }
    }
    __syncthreads();

    float mm[GH], inv[GH];
#pragma unroll
    for (int h = 0; h < GH; ++h) { mm[h] = s_m[h]; inv[h] = 1.0f / s_den[h]; }

    const int hd = (2 * tid) / C;          // head of this thread's channel pair
    float2 acc = make_float2(0.f, 0.f);

    for (int e0 = start; e0 < end; e0 += 64) {
        __syncthreads();
        if (tid < 64) {
            bool vld = (e0 + tid) < end;
            int s = vld ? csr_src[e0 + tid] : n;
            s_src[tid] = s;
            float4 as4 = *(const float4*)(a_s + s * GH);
            float l[GH] = {as4.x + adh[0], as4.y + adh[1], as4.z + adh[2], as4.w + adh[3]};
#pragma unroll
            for (int h = 0; h < GH; ++h) {
                float ll = l[h] > 0.f ? l[h] : 0.2f * l[h];
                s_al[h][tid] = vld ? __expf(ll - mm[h]) * inv[h] : 0.f;
            }
        }
        __syncthreads();
        int cnt = end - e0; if (cnt > 64) cnt = 64;
        int cnt4 = (cnt + 3) & ~3;
        for (int i = 0; i < cnt4; i += 4) {
            int4   ss = *(const int4*)&s_src[i];
            float4 aa = *(const float4*)&s_al[hd][i];
            const float2* p0 = (const float2*)(hfeat + (size_t)ss.x * HC) + tid;
            const float2* p1 = (const float2*)(hfeat + (size_t)ss.y * HC) + tid;
            const float2* p2 = (const float2*)(hfeat + (size_t)ss.z * HC) + tid;
            const float2* p3 = (const float2*)(hfeat + (size_t)ss.w * HC) + tid;
            float2 v0 = *p0, v1 = *p1, v2 = *p2, v3 = *p3;
            acc.x = fmaf(aa.x, v0.x, acc.x); acc.y = fmaf(aa.x, v0.y, acc.y);
            acc.x = fmaf(aa.y, v1.x, acc.x); acc.y = fmaf(aa.y, v1.y, acc.y);
            acc.x = fmaf(aa.z, v2.x, acc.x); acc.y = fmaf(aa.z, v2.y, acc.y);
            acc.x = fmaf(aa.w, v3.x, acc.x); acc.y = fmaf(aa.w, v3.y, acc.y);
        }
    }

    if (!FINAL) {
        float2 b2 = *(const float2*)(bias + 2 * tid);
        float vx = acc.x + b2.x, vy = acc.y + b2.y;
        vx = vx > 0.f ? vx : expm1f(vx);
        vy = vy > 0.f ? vy : expm1f(vy);
        *(float2*)(out + (size_t)n * HC + 2 * tid) = make_float2(vx, vy);
    } else {
        sacc[2 * tid]     = acc.x;
        sacc[2 * tid + 1] = acc.y;
        __syncthreads();
        if (tid < C) {
            float v = 0.f;
#pragma unroll
            for (int h = 0; h < GH; ++h) v += sacc[h * C + tid];
            out[(size_t)n * C + tid] = v * (1.0f / GH) + bias[tid];
        }
    }
}

// ---------------------------------------------------------------------------
extern "C" void kernel_launch(void* const* d_in, const int* in_sizes, int n_in,
                              void* d_out, int out_size, void* d_ws, size_t ws_size,
                              hipStream_t stream) {
    const float* x  = (const float*)d_in[0];
    const void*  ei = d_in[1];
    const float* W[4]  = {(const float*)d_in[2],  (const float*)d_in[6],
                          (const float*)d_in[10], (const float*)d_in[14]};
    const float* AS[4] = {(const float*)d_in[3],  (const float*)d_in[7],
                          (const float*)d_in[11], (const float*)d_in[15]};
    const float* AD[4] = {(const float*)d_in[4],  (const float*)d_in[8],
                          (const float*)d_in[12], (const float*)d_in[16]};
    const float* BI[4] = {(const float*)d_in[5],  (const float*)d_in[9],
                          (const float*)d_in[13], (const float*)d_in[17]};

    char*  w   = (char*)d_ws;
    size_t off = 0;
    auto alloc = [&](size_t b) -> char* {
        char* p = w + off;
        off += (b + 255) & ~(size_t)255;
        return p;
    };
    int*   flag    = (int*)alloc(4);
    int*   counts  = (int*)alloc((GN + 1) * sizeof(int));
    int*   offsets = (int*)alloc((GN + 1) * sizeof(int));
    int*   cursor  = (int*)alloc(GN * sizeof(int));
    int*   csr_src = (int*)alloc((size_t)GETOT * sizeof(int));
    float* a_s     = (float*)alloc((size_t)GN * GH * sizeof(float));
    float* a_d     = (float*)alloc((size_t)GN * GH * sizeof(float));
    float* hbuf    = (float*)alloc((size_t)GN * 512 * sizeof(float));     // 41 MB (GEMM out)
    float* obuf    = (float*)alloc((size_t)GN * 512 * sizeof(float));     // 41 MB (agg out)
    __hip_bfloat16* wthi = (__hip_bfloat16*)alloc((size_t)512 * 2016 * 2); // 2.06 MB
    __hip_bfloat16* wtlo = (__hip_bfloat16*)alloc((size_t)512 * 2016 * 2); // 2.06 MB
    (void)in_sizes; (void)n_in; (void)out_size; (void)ws_size;

    // ---- CSR by destination (layer-invariant) ----
    detect_dtype_kernel<<<1, 64, 0, stream>>>(ei, flag);
    hipMemsetAsync(counts, 0, (GN + 1) * sizeof(int), stream);
    int eblocks = (GETOT + 255) / 256;
    hist_kernel<<<eblocks, 256, 0, stream>>>(ei, flag, counts);
    scan_kernel<<<1, 1024, 0, stream>>>(counts, offsets, cursor);
    scatter_kernel<<<eblocks, 256, 0, stream>>>(ei, flag, cursor, csr_src);

    const dim3 tb(32, 8);
    const int MB = (GN + 127) / 128;   // 157 row blocks

    // ---- layer 0: 2000 -> 4x128 concat, ELU ----
    convert_wt<<<dim3(2016 / 32, 512 / 32), tb, 0, stream>>>(W[0], wthi, wtlo, 2000, 512, 2016);
    gemm_fused<<<dim3(512 / 128, MB), 256, 0, stream>>>(x, 2000, 2000, wthi, wtlo, 2016,
                                                        hbuf, GN, 512);
    att_sd_kernel<<<(GN * 64) / 256, 256, 0, stream>>>(hbuf, AS[0], AD[0], a_s, a_d, 128);
    gat_aggregate<128, false, 256><<<GN, 256, 0, stream>>>(hbuf, a_s, a_d, offsets, csr_src,
                                                           BI[0], obuf);
    // ---- layer 1: 512 -> 4x64 concat, ELU ----
    convert_wt<<<dim3(512 / 32, 256 / 32), tb, 0, stream>>>(W[1], wthi, wtlo, 512, 256, 512);
    gemm_fused<<<dim3(256 / 128, MB), 256, 0, stream>>>(obuf, 512, 512, wthi, wtlo, 512,
                                                        hbuf, GN, 256);
    att_sd_kernel<<<(GN * 64) / 256, 256, 0, stream>>>(hbuf, AS[1], AD[1], a_s, a_d, 64);
    gat_aggregate<64, false, 128><<<GN, 128, 0, stream>>>(hbuf, a_s, a_d, offsets, csr_src,
                                                          BI[1], obuf);
    // ---- layer 2: 256 -> 4x32 concat, ELU ----
    convert_wt<<<dim3(256 / 32, 128 / 32), tb, 0, stream>>>(W[2], wthi, wtlo, 256, 128, 256);
    gemm_fused<<<dim3(128 / 128, MB), 256, 0, stream>>>(obuf, 256, 256, wthi, wtlo, 256,
                                                        hbuf, GN, 128);
    att_sd_kernel<<<(GN * 64) / 256, 256, 0, stream>>>(hbuf, AS[2], AD[2], a_s, a_d, 32);
    gat_aggregate<32, false, 64><<<GN, 64, 0, stream>>>(hbuf, a_s, a_d, offsets, csr_src,
                                                        BI[2], obuf);
    // ---- layer 3: 128 -> 4x64 mean, no ELU ----
    convert_wt<<<dim3(128 / 32, 256 / 32), tb, 0, stream>>>(W[3], wthi, wtlo, 128, 256, 128);
    gemm_fused<<<dim3(256 / 128, MB), 256, 0, stream>>>(obuf, 128, 128, wthi, wtlo, 128,
                                                        hbuf, GN, 256);
    att_sd_kernel<<<(GN * 64) / 256, 256, 0, stream>>>(hbuf, AS[3], AD[3], a_s, a_d, 64);
    gat_aggregate<64, true, 128><<<GN, 128, 0, stream>>>(hbuf, a_s, a_d, offsets, csr_src,
                                                         BI[3], (float*)d_out);
}